// Round 4
// baseline (105.240 us; speedup 1.0000x reference)
//
#include <hip/hip_runtime.h>
#include <math.h>

typedef unsigned short u16;
typedef unsigned int u32;
typedef __attribute__((ext_vector_type(2))) float f32x2;
typedef __attribute__((ext_vector_type(4))) float f32x4;
typedef __attribute__((ext_vector_type(8))) short bf16x8;

// adjacency-collapse constants: u = 1/(6+1e-8); s = 1+6u; c1=1/s; c2=c1^2; a=u/s; a1c=a*(1+c1)
#define U_CONST   0.16666666638888889f
#define C1_CONST  0.5000000004166667f
#define C2_CONST  0.2500000004166667f
#define A_CONST   0.08333333326388889f
#define A1C_CONST 0.12499999993055555f

__device__ __forceinline__ float bf2f(u16 u){ union{u32 i; float f;} v; v.i=((u32)u)<<16; return v.f; }
__device__ __forceinline__ u16 f2bf(float f){ union{float f; u32 i;} v; v.f=f; u32 x=v.i;
  return (u16)((x + 0x7FFFu + ((x>>16)&1u)) >> 16); }  // RNE
__device__ __forceinline__ float gelu_f(float x){ return 0.5f*x*(1.0f+erff(x*0.7071067811865476f)); }

__device__ __forceinline__ bf16x8 pack8(f32x4 a, f32x4 b){
  union { bf16x8 v; u16 e[8]; } r;
  r.e[0]=f2bf(a[0]); r.e[1]=f2bf(a[1]); r.e[2]=f2bf(a[2]); r.e[3]=f2bf(a[3]);
  r.e[4]=f2bf(b[0]); r.e[5]=f2bf(b[1]); r.e[6]=f2bf(b[2]); r.e[7]=f2bf(b[3]);
  return r.v;
}

// in-wave LayerNorm over 128 cols: lane holds col (n<<4)+cl, rows cq*4+j; row sums via 16-lane shfl
template<bool GELU>
__device__ __forceinline__ void ln_rows(f32x4 (&acc)[8], const float* __restrict__ gvec,
                                        const float* __restrict__ bvec, int cl){
  float sm[4]={0,0,0,0}, sq[4]={0,0,0,0};
  #pragma unroll
  for (int n=0;n<8;n++)
    #pragma unroll
    for (int j=0;j<4;j++){ float x = acc[n][j]; sm[j]+=x; sq[j]+=x*x; }
  #pragma unroll
  for (int j=0;j<4;j++){
    #pragma unroll
    for (int off=1; off<16; off<<=1){ sm[j]+=__shfl_xor(sm[j],off); sq[j]+=__shfl_xor(sq[j],off); }
    float m = sm[j]*0.0078125f;
    float r = rsqrtf(sq[j]*0.0078125f - m*m + 1e-5f);
    sm[j]=m; sq[j]=r;
  }
  #pragma unroll
  for (int n=0;n<8;n++){
    float gg = gvec[(n<<4)+cl], be = bvec[(n<<4)+cl];
    #pragma unroll
    for (int j=0;j<4;j++){
      float y = (acc[n][j]-sm[j])*sq[j]*gg + be;
      acc[n][j] = GELU ? gelu_f(y) : y;
    }
  }
}

// ---------- prep: 5 weight slots, bf16, LINEAR W^T (row h, col f) ----------
// slots (u16 offset): 0:W1  16384:Wx  32768:Wsv  49152:sW1a  65536:sW1b'(=u*sW1[128:])
__global__ void k_prep(const float* __restrict__ W1, const float* __restrict__ chw,
                       const float* __restrict__ sW1, u16* __restrict__ WT5){
  int i = blockIdx.x*256 + threadIdx.x;          // i = f*128+h
  int dst = ((i&127)<<7) + (i>>7);               // h*128+f
  float w0 = chw[i], w1 = chw[16384+i], w2 = chw[32768+i];
  WT5[dst]         = f2bf(W1[i]);
  WT5[16384+dst]   = f2bf(w0 + C1_CONST*w1 + C2_CONST*w2);
  WT5[32768+dst]   = f2bf(A_CONST*w1 + A1C_CONST*w2);
  WT5[49152+dst]   = f2bf(sW1[i]);
  WT5[65536+dst]   = f2bf(U_CONST*sW1[16384+i]);
}

// adj = softmax(const) = 1/(6+1e-8) (LN over size-1 axis kills the data dependence)
__global__ void k_adj(float* __restrict__ adj){
  adj[blockIdx.x*256 + threadIdx.x] = 0.16666667f;
}

// ---------- K_A: fe_proj. 8 groups (48 rows) / block, 3 waves, A direct from X_de ----------
__global__ __launch_bounds__(192, 4)
void k_fe(const float* __restrict__ X_de, const u16* __restrict__ WT5,
          const float* __restrict__ b1, const float* __restrict__ ln1g, const float* __restrict__ ln1b,
          float* __restrict__ out, u16* __restrict__ Sbuf)
{
  __shared__ __align__(8) u16 Ab[48*128];
  const int tid = threadIdx.x, w = tid>>6, lane = tid&63, cl = lane&15, cq = lane>>4;
  const int g0 = blockIdx.x<<3;
  const int row0 = blockIdx.x*48 + (w<<4);
  // this lane's A row: global row -> (b, c, t)
  const int grow = row0 + cl;
  const u32 grp = ((u32)grow * 43691u) >> 18;        // grow/6 (exact for grow < 2^17)
  const int c = grow - (int)grp*6;
  const float* xrow = X_de + (((size_t)((int)(grp>>7)*6 + c)<<7) + (grp&127))*128 + (cq<<3);
  const u16* wbase = WT5 + (cl<<7) + (cq<<3);        // slot 0 = W1

  f32x4 acc[8];
  #pragma unroll
  for (int n=0;n<8;n++) acc[n]=(f32x4){0.f,0.f,0.f,0.f};
  #pragma unroll
  for (int kt=0;kt<4;kt++){
    f32x4 alo = *(const f32x4*)(xrow + (kt<<5));
    f32x4 ahi = *(const f32x4*)(xrow + (kt<<5) + 4);
    bf16x8 af = pack8(alo, ahi);
    #pragma unroll
    for (int n=0;n<8;n++){
      bf16x8 bfr = *(const bf16x8*)(wbase + (n<<11) + (kt<<5));
      acc[n] = __builtin_amdgcn_mfma_f32_16x16x32_bf16(af, bfr, acc[n],0,0,0);
    }
  }
  #pragma unroll
  for (int n=0;n<8;n++){ float bv = b1[(n<<4)+cl];
    #pragma unroll
    for (int j=0;j<4;j++) acc[n][j] += bv; }
  ln_rows<true>(acc, ln1g, ln1b, cl);
  float* Xn = out + 1343488 + (size_t)blockIdx.x*48*128;
  #pragma unroll
  for (int n=0;n<8;n++)
    #pragma unroll
    for (int j=0;j<4;j++){
      int R = (w<<4)+(cq<<2)+j;
      float y = acc[n][j], yo = __shfl_xor(y,1);
      if (!(cl&1)){
        int col = (n<<4)+cl;
        *(f32x2*)(Xn + (size_t)R*128 + col) = (f32x2){y,yo};
        *(u32*)((char*)Ab + (R<<8) + (col<<1)) = (u32)f2bf(y)|((u32)f2bf(yo)<<16);
      }
    }
  __syncthreads();
  for (int idx = tid; idx < 1024; idx += 192){
    int gl = idx>>7, col = idx&127;
    float s = 0.f;
    #pragma unroll
    for (int cc=0;cc<6;cc++) s += bf2f(Ab[((6*gl+cc)<<7)+col]);
    Sbuf[((size_t)(g0+gl)<<7)+col] = f2bf(s);
  }
}

// ---------- K_B/K_D: Out[8192][128] = Abf@Wslot + bias. No LDS, no barriers ----------
__global__ __launch_bounds__(256, 4)
void k_small(const u16* __restrict__ Abf, const u16* __restrict__ Wslot,
             const float* __restrict__ bias, float* __restrict__ Out)
{
  const int tid = threadIdx.x, w = tid>>6, lane = tid&63, cl = lane&15, cq = lane>>4;
  const int m0 = ((blockIdx.x<<2)+w)<<4;
  const u16* arow  = Abf + (((size_t)(m0+cl))<<7) + (cq<<3);
  const u16* wbase = Wslot + (cl<<7) + (cq<<3);
  f32x4 acc[8];
  #pragma unroll
  for (int n=0;n<8;n++) acc[n]=(f32x4){0.f,0.f,0.f,0.f};
  #pragma unroll
  for (int kt=0;kt<4;kt++){
    bf16x8 af = *(const bf16x8*)(arow + (kt<<5));
    #pragma unroll
    for (int n=0;n<8;n++){
      bf16x8 bfr = *(const bf16x8*)(wbase + (n<<11) + (kt<<5));
      acc[n] = __builtin_amdgcn_mfma_f32_16x16x32_bf16(af, bfr, acc[n],0,0,0);
    }
  }
  #pragma unroll
  for (int n=0;n<8;n++){
    float bv = bias[(n<<4)+cl];
    #pragma unroll
    for (int j=0;j<4;j++)
      Out[(((size_t)(m0+(cq<<2)+j))<<7) + (n<<4)+cl] = acc[n][j] + bv;
  }
}

// ---------- K_C: cheb. g = LN(Xn@Wx + T2[group]); Sg = group sums ----------
__global__ __launch_bounds__(192, 4)
void k_cheb(const u16* __restrict__ WT5, const float* __restrict__ T2,
            const float* __restrict__ clng, const float* __restrict__ clnb,
            float* __restrict__ out, u16* __restrict__ Sgbuf)
{
  __shared__ __align__(8) u16 Ab[48*128];
  __shared__ float Tl[1024];
  const int tid = threadIdx.x, w = tid>>6, lane = tid&63, cl = lane&15, cq = lane>>4;
  const int g0 = blockIdx.x<<3;
  for (int idx = tid; idx < 1024; idx += 192) Tl[idx] = T2[(((size_t)g0)<<7)+idx];

  const float* xrow = out + 1343488 + ((size_t)(blockIdx.x*48 + (w<<4) + cl))*128 + (cq<<3);
  const u16* wbase = WT5 + 16384 + (cl<<7) + (cq<<3);   // Wx
  f32x4 acc[8];
  #pragma unroll
  for (int n=0;n<8;n++) acc[n]=(f32x4){0.f,0.f,0.f,0.f};
  #pragma unroll
  for (int kt=0;kt<4;kt++){
    f32x4 alo = *(const f32x4*)(xrow + (kt<<5));
    f32x4 ahi = *(const f32x4*)(xrow + (kt<<5) + 4);
    bf16x8 af = pack8(alo, ahi);
    #pragma unroll
    for (int n=0;n<8;n++){
      bf16x8 bfr = *(const bf16x8*)(wbase + (n<<11) + (kt<<5));
      acc[n] = __builtin_amdgcn_mfma_f32_16x16x32_bf16(af, bfr, acc[n],0,0,0);
    }
  }
  __syncthreads();                                      // Tl ready
  #pragma unroll
  for (int j=0;j<4;j++){
    int R = (w<<4)+(cq<<2)+j;
    int lgl = (R*171)>>10;                              // R/6 for R<48
    #pragma unroll
    for (int n=0;n<8;n++) acc[n][j] += Tl[(lgl<<7)+(n<<4)+cl];
  }
  ln_rows<false>(acc, clng, clnb, cl);
  float* G = out + 7634944 + (size_t)blockIdx.x*48*128;
  #pragma unroll
  for (int n=0;n<8;n++)
    #pragma unroll
    for (int j=0;j<4;j++){
      int R = (w<<4)+(cq<<2)+j;
      float y = acc[n][j], yo = __shfl_xor(y,1);
      if (!(cl&1)){
        int col = (n<<4)+cl;
        *(f32x2*)(G + (size_t)R*128 + col) = (f32x2){y,yo};
        *(u32*)((char*)Ab + (R<<8) + (col<<1)) = (u32)f2bf(y)|((u32)f2bf(yo)<<16);
      }
    }
  __syncthreads();
  for (int idx = tid; idx < 1024; idx += 192){
    int gl = idx>>7, col = idx&127;
    float s = 0.f;
    #pragma unroll
    for (int cc=0;cc<6;cc++) s += bf2f(Ab[((6*gl+cc)<<7)+col]);
    Sgbuf[((size_t)(g0+gl)<<7)+col] = f2bf(s);
  }
}

// ---------- K_E: satt + epoch ----------
__global__ __launch_bounds__(192, 4)
void k_satt(const u16* __restrict__ WT5, const float* __restrict__ T4,
            const float* __restrict__ slng, const float* __restrict__ slnb,
            const float* __restrict__ sW2, const float* __restrict__ sb2p,
            float* __restrict__ out)
{
  __shared__ float Tl[1024];
  __shared__ float attb[48];
  const int tid = threadIdx.x, w = tid>>6, lane = tid&63, cl = lane&15, cq = lane>>4;
  const int g0 = blockIdx.x<<3;
  for (int idx = tid; idx < 1024; idx += 192) Tl[idx] = T4[(((size_t)g0)<<7)+idx];

  const float* grow_p = out + 7634944 + ((size_t)(blockIdx.x*48 + (w<<4) + cl))*128 + (cq<<3);
  const u16* wbase = WT5 + 49152 + (cl<<7) + (cq<<3);   // sW1a
  f32x4 acc[8];
  #pragma unroll
  for (int n=0;n<8;n++) acc[n]=(f32x4){0.f,0.f,0.f,0.f};
  #pragma unroll
  for (int kt=0;kt<4;kt++){
    f32x4 alo = *(const f32x4*)(grow_p + (kt<<5));
    f32x4 ahi = *(const f32x4*)(grow_p + (kt<<5) + 4);
    bf16x8 af = pack8(alo, ahi);
    #pragma unroll
    for (int n=0;n<8;n++){
      bf16x8 bfr = *(const bf16x8*)(wbase + (n<<11) + (kt<<5));
      acc[n] = __builtin_amdgcn_mfma_f32_16x16x32_bf16(af, bfr, acc[n],0,0,0);
    }
  }
  __syncthreads();                                      // Tl ready
  #pragma unroll
  for (int j=0;j<4;j++){
    int R = (w<<4)+(cq<<2)+j;
    int lgl = (R*171)>>10;
    #pragma unroll
    for (int n=0;n<8;n++) acc[n][j] += Tl[(lgl<<7)+(n<<4)+cl];
  }
  ln_rows<true>(acc, slng, slnb, cl);
  float z[4] = {0,0,0,0};
  #pragma unroll
  for (int n=0;n<8;n++){ float wv = sW2[(n<<4)+cl];
    #pragma unroll
    for (int j=0;j<4;j++) z[j] += acc[n][j]*wv; }
  float s2 = sb2p[0];
  #pragma unroll
  for (int j=0;j<4;j++){
    #pragma unroll
    for (int off=1; off<16; off<<=1) z[j] += __shfl_xor(z[j], off);
    z[j] = 1.0f/(1.0f + expf(-(z[j] + s2)));
    if (cl == 0) attb[(w<<4)+(cq<<2)+j] = z[j];
  }
  __syncthreads();
  const float* G = out + 7634944 + (size_t)blockIdx.x*48*128;
  for (int idx = tid; idx < 1024; idx += 192){
    int gl = idx>>7, col = idx&127;
    float s = 0.f;
    #pragma unroll
    for (int cc=0;cc<6;cc++){ int r = 6*gl+cc; s += attb[r]*G[(size_t)r*128 + col]; }
    out[((size_t)(g0+gl)<<7) + col] = s*(1.0f/6.0f);
  }
}

// ---------- launcher ----------
extern "C" void kernel_launch(void* const* d_in, const int* in_sizes, int n_in,
                              void* d_out, int out_size, void* d_ws, size_t ws_size,
                              hipStream_t stream){
  const float* X_de = (const float*)d_in[0];
  const float* W1   = (const float*)d_in[1];
  const float* b1   = (const float*)d_in[2];
  const float* ln1g = (const float*)d_in[3];
  const float* ln1b = (const float*)d_in[4];
  // d_in[5..8] (aw, ab, aln_g, aln_b) mathematically dead: LN over size-1 axis == aln_b
  const float* chw  = (const float*)d_in[9];
  const float* chb  = (const float*)d_in[10];
  const float* clng = (const float*)d_in[11];
  const float* clnb = (const float*)d_in[12];
  const float* sW1  = (const float*)d_in[13];
  const float* sb1  = (const float*)d_in[14];
  const float* slng = (const float*)d_in[15];
  const float* slnb = (const float*)d_in[16];
  const float* sW2  = (const float*)d_in[17];
  const float* sb2  = (const float*)d_in[18];

  float* out = (float*)d_out;
  char* wsb  = (char*)d_ws;
  u16*   WT5   = (u16*)wsb;                   // 160KB (5 slots bf16 W^T)
  u16*   Sbuf  = (u16*)(wsb + 0x40000);       // 2MB  (S  bf16 [8192][128])
  u16*   Sgbuf = (u16*)(wsb + 0x240000);      // 2MB  (Sg bf16)
  float* T2    = (float*)(wsb + 0x440000);    // 4MB
  float* T4    = (float*)(wsb + 0x840000);    // 4MB  (total 12.25MB)

  hipLaunchKernelGGL(k_prep,  dim3(64),   dim3(256), 0, stream, W1, chw, sW1, WT5);
  hipLaunchKernelGGL(k_adj,   dim3(1152), dim3(256), 0, stream, out + 1048576);
  hipLaunchKernelGGL(k_fe,    dim3(1024), dim3(192), 0, stream, X_de, WT5, b1, ln1g, ln1b, out, Sbuf);
  hipLaunchKernelGGL(k_small, dim3(128),  dim3(256), 0, stream, Sbuf,  WT5 + 32768, chb, T2);
  hipLaunchKernelGGL(k_cheb,  dim3(1024), dim3(192), 0, stream, WT5, T2, clng, clnb, out, Sgbuf);
  hipLaunchKernelGGL(k_small, dim3(128),  dim3(256), 0, stream, Sgbuf, WT5 + 65536, sb1, T4);
  hipLaunchKernelGGL(k_satt,  dim3(1024), dim3(192), 0, stream, WT5, T4, slng, slnb, sW2, sb2, out);
}

// Round 6
// 69.826 us; speedup vs baseline: 1.5072x; 1.5072x over previous
//
#include <hip/hip_runtime.h>
#include <math.h>

typedef unsigned short u16;
typedef unsigned int u32;
typedef __attribute__((ext_vector_type(2))) float f32x2;
typedef __attribute__((ext_vector_type(4))) float f32x4;
typedef __attribute__((ext_vector_type(8))) short bf16x8;
typedef __attribute__((ext_vector_type(4))) u32 u32x4;

// adjacency-collapse constants: u = 1/(6+1e-8); s = 1+6u; c1=1/s; c2=c1^2; a=u/s; a1c=a*(1+c1)
#define U_CONST   0.16666666638888889f
#define C1_CONST  0.5000000004166667f
#define C2_CONST  0.2500000004166667f
#define A_CONST   0.08333333326388889f
#define A1C_CONST 0.12499999993055555f

__device__ __forceinline__ float bf2f(u16 u){ union{u32 i; float f;} v; v.i=((u32)u)<<16; return v.f; }
__device__ __forceinline__ u16 f2bf(float f){ union{float f; u32 i;} v; v.f=f; u32 x=v.i;
  return (u16)((x + 0x7FFFu + ((x>>16)&1u)) >> 16); }  // RNE

// fast gelu: erf via Abramowitz-Stegun 7.1.26 (|err| <= 1.5e-7), native exp/rcp.
// NOTE: erf argument is x/sqrt(2) — R5 bug was missing this scale.
__device__ __forceinline__ float gelu_f(float x){
  float ax = fabsf(x) * 0.7071067811865476f;
  float t  = __builtin_amdgcn_rcpf(fmaf(0.3275911f, ax, 1.0f));
  float p  = t*fmaf(t, fmaf(t, fmaf(t, fmaf(t, 1.061405429f, -1.453152027f),
                                    1.421413741f), -0.284496736f), 0.254829592f);
  float er = fmaf(-p, __expf(-ax*ax), 1.0f);
  er = copysignf(er, x);
  return 0.5f*x*(1.0f+er);
}
__device__ __forceinline__ float sigmoid_f(float z){
  return __builtin_amdgcn_rcpf(1.0f + __expf(-z));
}

__device__ __forceinline__ bf16x8 pack8(f32x4 a, f32x4 b){
  union { bf16x8 v; u16 e[8]; } r;
  r.e[0]=f2bf(a[0]); r.e[1]=f2bf(a[1]); r.e[2]=f2bf(a[2]); r.e[3]=f2bf(a[3]);
  r.e[4]=f2bf(b[0]); r.e[5]=f2bf(b[1]); r.e[6]=f2bf(b[2]); r.e[7]=f2bf(b[3]);
  return r.v;
}

// in-wave LayerNorm over 128 cols: lane holds col (n<<4)+cl, rows cq*4+j (16-lane shfl reduce)
template<bool GELU>
__device__ __forceinline__ void ln_rows(f32x4 (&acc)[8], const float* __restrict__ gvec,
                                        const float* __restrict__ bvec, int cl){
  float sm[4]={0,0,0,0}, sq[4]={0,0,0,0};
  #pragma unroll
  for (int n=0;n<8;n++)
    #pragma unroll
    for (int j=0;j<4;j++){ float x = acc[n][j]; sm[j]+=x; sq[j]+=x*x; }
  #pragma unroll
  for (int j=0;j<4;j++){
    #pragma unroll
    for (int off=1; off<16; off<<=1){ sm[j]+=__shfl_xor(sm[j],off); sq[j]+=__shfl_xor(sq[j],off); }
    float m = sm[j]*0.0078125f;
    float r = rsqrtf(sq[j]*0.0078125f - m*m + 1e-5f);
    sm[j]=m; sq[j]=r;
  }
  #pragma unroll
  for (int n=0;n<8;n++){
    float gg = gvec[(n<<4)+cl], be = bvec[(n<<4)+cl];
    #pragma unroll
    for (int j=0;j<4;j++){
      float y = (acc[n][j]-sm[j])*sq[j]*gg + be;
      acc[n][j] = GELU ? gelu_f(y) : y;
    }
  }
}

// ---------- prep: 5 weight slots, bf16, LINEAR W^T (row h=out col, col f=k) ----------
// slots (u16 offset): 0:W1  16384:Wx  32768:Wsv  49152:sW1a  65536:sW1b'(=u*sW1[128:])
__global__ void k_prep(const float* __restrict__ W1, const float* __restrict__ chw,
                       const float* __restrict__ sW1, u16* __restrict__ WT5){
  int i = blockIdx.x*256 + threadIdx.x;          // i = f*128+h
  int dst = ((i&127)<<7) + (i>>7);               // h*128+f
  float w0 = chw[i], w1 = chw[16384+i], w2 = chw[32768+i];
  WT5[dst]         = f2bf(W1[i]);
  WT5[16384+dst]   = f2bf(w0 + C1_CONST*w1 + C2_CONST*w2);
  WT5[32768+dst]   = f2bf(A_CONST*w1 + A1C_CONST*w2);
  WT5[49152+dst]   = f2bf(sW1[i]);
  WT5[65536+dst]   = f2bf(U_CONST*sW1[16384+i]);
}

// adj = softmax(const) = 1/(6+1e-8) (LN over size-1 axis kills the data dependence)
__global__ void k_adj(float* __restrict__ adj){
  adj[blockIdx.x*256 + threadIdx.x] = 0.16666667f;
}

// ---------- shared-LDS W staging (swizzled) + B-frag accessor ----------
__device__ __forceinline__ void stageW(u16* Wb, const u16* __restrict__ slot, int tid){
  const u32x4* src = (const u32x4*)slot;          // 2048 x 16B
  #pragma unroll
  for (int it=0; it<8; ++it){
    int i = tid + (it<<8);
    int h = i >> 4, s = i & 15;
    u32x4 v = src[i];
    *(u32x4*)((char*)Wb + (h<<8) + ((s ^ (h&7))<<4)) = v;
  }
}
__device__ __forceinline__ bf16x8 bfrag(const u16* Wb, int col, int kt, int cq){
  int s = (kt<<2) + cq;
  return *(const bf16x8*)((const char*)Wb + (col<<8) + ((s ^ (col&7))<<4));
}

// wave-private group sums over rows (rows 0-5 -> s0, 6-11 -> s1), cross-cq shfl
__device__ __forceinline__ void gsum(const f32x4 (&acc)[8], float (&s0)[8], float (&s1)[8], int cq){
  #pragma unroll
  for (int n=0;n<8;n++){
    float a=0.f, b=0.f;
    #pragma unroll
    for (int j=0;j<4;j++){
      int row = (cq<<2)+j;
      float y = acc[n][j];
      a += (row<6)? y : 0.f;
      b += (row>=6 && row<12)? y : 0.f;
    }
    a += __shfl_xor(a,16); a += __shfl_xor(a,32);
    b += __shfl_xor(b,16); b += __shfl_xor(b,32);
    s0[n]=a; s1[n]=b;
  }
}

// ---------- K_A: fe_proj. 4 waves/block, wave = 2 groups (12 rows of 16-tile) ----------
__global__ __launch_bounds__(256, 4)
void k_fe(const float* __restrict__ X_de, const u16* __restrict__ WT5,
          const float* __restrict__ b1, const float* __restrict__ ln1g, const float* __restrict__ ln1b,
          float* __restrict__ Xn, u16* __restrict__ Sbuf)
{
  __shared__ __align__(16) u16 Wb[128*128];
  const int tid = threadIdx.x, w = tid>>6, lane = tid&63, cl = lane&15, cq = lane>>4;
  const int R0 = blockIdx.x*48 + w*12;
  const int g0 = blockIdx.x*8 + w*2;

  // A preload (before barrier: overlap with W staging)
  int rl = (cl < 12) ? cl : 0;
  int grow = R0 + rl;
  u32 grp = ((u32)grow * 43691u) >> 18;            // grow/6
  int c = grow - (int)grp*6;
  const float* xrow = X_de + (((size_t)(((int)(grp>>7))*6 + c)<<7) + (int)(grp&127))*128 + (cq<<3);
  bf16x8 af[4];
  #pragma unroll
  for (int kt=0;kt<4;kt++){
    f32x4 lo = *(const f32x4*)(xrow + (kt<<5));
    f32x4 hi = *(const f32x4*)(xrow + (kt<<5) + 4);
    af[kt] = pack8(lo, hi);
  }
  stageW(Wb, WT5, tid);
  __syncthreads();

  f32x4 acc[8];
  #pragma unroll
  for (int n=0;n<8;n++) acc[n]=(f32x4){0.f,0.f,0.f,0.f};
  #pragma unroll
  for (int kt=0;kt<4;kt++)
    #pragma unroll
    for (int n=0;n<8;n++)
      acc[n] = __builtin_amdgcn_mfma_f32_16x16x32_bf16(af[kt], bfrag(Wb,(n<<4)+cl,kt,cq), acc[n],0,0,0);

  #pragma unroll
  for (int n=0;n<8;n++){ float bv = b1[(n<<4)+cl];
    #pragma unroll
    for (int j=0;j<4;j++) acc[n][j] += bv; }
  ln_rows<true>(acc, ln1g, ln1b, cl);

  // store Xn (f32x2 pairs, rows<12)
  float* Xr = Xn + (size_t)R0*128;
  #pragma unroll
  for (int n=0;n<8;n++)
    #pragma unroll
    for (int j=0;j<4;j++){
      int row=(cq<<2)+j;
      float y=acc[n][j], yo=__shfl_xor(y,1);
      if (row<12 && !(cl&1))
        *(f32x2*)(Xr + (size_t)row*128 + (n<<4)+cl) = (f32x2){y,yo};
    }
  // S (group sums) -> bf16
  float s0[8], s1[8];
  gsum(acc, s0, s1, cq);
  #pragma unroll
  for (int n=0;n<8;n++){
    float a1_ = __shfl_xor(s0[n],1), b1_ = __shfl_xor(s1[n],1);
    if (cq==0 && !(cl&1)){
      int cidx = ((n<<4)+cl)>>1;
      ((u32*)Sbuf)[(size_t)g0*64 + cidx]     = (u32)f2bf(s0[n]) | ((u32)f2bf(a1_)<<16);
      ((u32*)Sbuf)[(size_t)(g0+1)*64 + cidx] = (u32)f2bf(s1[n]) | ((u32)f2bf(b1_)<<16);
    }
  }
}

// ---------- K_B/K_D: Out[8192][128] = Abf@Wslot + bias (B direct from global) ----------
__global__ __launch_bounds__(256, 4)
void k_small(const u16* __restrict__ Abf, const u16* __restrict__ Wslot,
             const float* __restrict__ bias, float* __restrict__ Out)
{
  const int tid = threadIdx.x, w = tid>>6, lane = tid&63, cl = lane&15, cq = lane>>4;
  const int m0 = ((blockIdx.x<<2)+w)<<4;
  const u16* arow  = Abf + (((size_t)(m0+cl))<<7) + (cq<<3);
  const u16* wbase = Wslot + (cl<<7) + (cq<<3);
  f32x4 acc[8];
  #pragma unroll
  for (int n=0;n<8;n++) acc[n]=(f32x4){0.f,0.f,0.f,0.f};
  #pragma unroll
  for (int kt=0;kt<4;kt++){
    bf16x8 af = *(const bf16x8*)(arow + (kt<<5));
    #pragma unroll
    for (int n=0;n<8;n++){
      bf16x8 bfr = *(const bf16x8*)(wbase + (n<<11) + (kt<<5));
      acc[n] = __builtin_amdgcn_mfma_f32_16x16x32_bf16(af, bfr, acc[n],0,0,0);
    }
  }
  #pragma unroll
  for (int n=0;n<8;n++){
    float bv = bias[(n<<4)+cl];
    #pragma unroll
    for (int j=0;j<4;j++)
      Out[(((size_t)(m0+(cq<<2)+j))<<7) + (n<<4)+cl] = acc[n][j] + bv;
  }
}

// ---------- K_C: cheb. g = LN(Xn@Wx + T2[group]); Sg group sums ----------
__global__ __launch_bounds__(256, 4)
void k_cheb(const float* __restrict__ Xn, const u16* __restrict__ WT5,
            const float* __restrict__ T2, const float* __restrict__ clng, const float* __restrict__ clnb,
            float* __restrict__ G, u16* __restrict__ Sgbuf)
{
  __shared__ __align__(16) u16 Wb[128*128];
  const int tid = threadIdx.x, w = tid>>6, lane = tid&63, cl = lane&15, cq = lane>>4;
  const int R0 = blockIdx.x*48 + w*12;
  const int g0 = blockIdx.x*8 + w*2;

  int rl = (cl < 12) ? cl : 0;
  const float* xrow = Xn + (size_t)(R0+rl)*128 + (cq<<3);
  bf16x8 af[4];
  #pragma unroll
  for (int kt=0;kt<4;kt++){
    f32x4 lo = *(const f32x4*)(xrow + (kt<<5));
    f32x4 hi = *(const f32x4*)(xrow + (kt<<5) + 4);
    af[kt] = pack8(lo, hi);
  }
  stageW(Wb, WT5 + 16384, tid);                        // Wx
  __syncthreads();

  f32x4 acc[8];
  #pragma unroll
  for (int n=0;n<8;n++) acc[n]=(f32x4){0.f,0.f,0.f,0.f};
  #pragma unroll
  for (int kt=0;kt<4;kt++)
    #pragma unroll
    for (int n=0;n<8;n++)
      acc[n] = __builtin_amdgcn_mfma_f32_16x16x32_bf16(af[kt], bfrag(Wb,(n<<4)+cl,kt,cq), acc[n],0,0,0);

  #pragma unroll
  for (int n=0;n<8;n++){
    float ta = T2[((size_t)g0<<7) + (n<<4)+cl];
    float tb = T2[((size_t)(g0+1)<<7) + (n<<4)+cl];
    #pragma unroll
    for (int j=0;j<4;j++){
      int row=(cq<<2)+j;
      acc[n][j] += (row<6)? ta : tb;
    }
  }
  ln_rows<false>(acc, clng, clnb, cl);

  float* Gr = G + (size_t)R0*128;
  #pragma unroll
  for (int n=0;n<8;n++)
    #pragma unroll
    for (int j=0;j<4;j++){
      int row=(cq<<2)+j;
      float y=acc[n][j], yo=__shfl_xor(y,1);
      if (row<12 && !(cl&1))
        *(f32x2*)(Gr + (size_t)row*128 + (n<<4)+cl) = (f32x2){y,yo};
    }
  float s0[8], s1[8];
  gsum(acc, s0, s1, cq);
  #pragma unroll
  for (int n=0;n<8;n++){
    float a1_ = __shfl_xor(s0[n],1), b1_ = __shfl_xor(s1[n],1);
    if (cq==0 && !(cl&1)){
      int cidx = ((n<<4)+cl)>>1;
      ((u32*)Sgbuf)[(size_t)g0*64 + cidx]     = (u32)f2bf(s0[n]) | ((u32)f2bf(a1_)<<16);
      ((u32*)Sgbuf)[(size_t)(g0+1)*64 + cidx] = (u32)f2bf(s1[n]) | ((u32)f2bf(b1_)<<16);
    }
  }
}

// ---------- K_E: satt + epoch ----------
__global__ __launch_bounds__(256, 4)
void k_satt(const float* __restrict__ G, const u16* __restrict__ WT5,
            const float* __restrict__ T4, const float* __restrict__ slng, const float* __restrict__ slnb,
            const float* __restrict__ sW2, const float* __restrict__ sb2p,
            float* __restrict__ epoch)
{
  __shared__ __align__(16) u16 Wb[128*128];
  const int tid = threadIdx.x, w = tid>>6, lane = tid&63, cl = lane&15, cq = lane>>4;
  const int R0 = blockIdx.x*48 + w*12;
  const int g0 = blockIdx.x*8 + w*2;

  int rl = (cl < 12) ? cl : 0;
  const float* grow_p = G + (size_t)(R0+rl)*128 + (cq<<3);
  bf16x8 af[4];
  #pragma unroll
  for (int kt=0;kt<4;kt++){
    f32x4 lo = *(const f32x4*)(grow_p + (kt<<5));
    f32x4 hi = *(const f32x4*)(grow_p + (kt<<5) + 4);
    af[kt] = pack8(lo, hi);
  }
  stageW(Wb, WT5 + 49152, tid);                        // sW1a
  __syncthreads();

  f32x4 acc[8];
  #pragma unroll
  for (int n=0;n<8;n++) acc[n]=(f32x4){0.f,0.f,0.f,0.f};
  #pragma unroll
  for (int kt=0;kt<4;kt++)
    #pragma unroll
    for (int n=0;n<8;n++)
      acc[n] = __builtin_amdgcn_mfma_f32_16x16x32_bf16(af[kt], bfrag(Wb,(n<<4)+cl,kt,cq), acc[n],0,0,0);

  #pragma unroll
  for (int n=0;n<8;n++){
    float ta = T4[((size_t)g0<<7) + (n<<4)+cl];
    float tb = T4[((size_t)(g0+1)<<7) + (n<<4)+cl];
    #pragma unroll
    for (int j=0;j<4;j++){
      int row=(cq<<2)+j;
      acc[n][j] += (row<6)? ta : tb;
    }
  }
  ln_rows<true>(acc, slng, slnb, cl);

  // att per row: z = h . sW2 + sb2 -> sigmoid
  float z0=0,z1=0,z2=0,z3=0;
  #pragma unroll
  for (int n=0;n<8;n++){
    float wv = sW2[(n<<4)+cl];
    z0 = fmaf(acc[n][0], wv, z0); z1 = fmaf(acc[n][1], wv, z1);
    z2 = fmaf(acc[n][2], wv, z2); z3 = fmaf(acc[n][3], wv, z3);
  }
  #pragma unroll
  for (int off=1; off<16; off<<=1){
    z0 += __shfl_xor(z0,off); z1 += __shfl_xor(z1,off);
    z2 += __shfl_xor(z2,off); z3 += __shfl_xor(z3,off);
  }
  float s2 = sb2p[0];
  float a0 = sigmoid_f(z0+s2), a1 = sigmoid_f(z1+s2), a2 = sigmoid_f(z2+s2), a3 = sigmoid_f(z3+s2);

  // broadcast att for rows 0..11 (src lane = (r>>2)*16, value index r&3)
  float attr[12];
  #pragma unroll
  for (int r=0;r<12;r++){
    int src = (r>>2)<<4;
    float v = (r&3)==0 ? a0 : (r&3)==1 ? a1 : (r&3)==2 ? a2 : a3;
    attr[r] = __shfl(v, src);
  }
  // epoch: coalesced f32x2 re-read of g rows (L3-hot), 2 cols/lane
  const int c2 = lane<<1;
  const float* gp = G + (size_t)R0*128 + c2;
  #pragma unroll
  for (int gi=0; gi<2; ++gi){
    float ex=0.f, ey=0.f;
    #pragma unroll
    for (int i=0;i<6;i++){
      f32x2 v = *(const f32x2*)(gp + (size_t)(gi*6+i)*128);
      ex = fmaf(attr[gi*6+i], v.x, ex);
      ey = fmaf(attr[gi*6+i], v.y, ey);
    }
    *(f32x2*)(epoch + (size_t)(g0+gi)*128 + c2) = (f32x2){ex*(1.0f/6.0f), ey*(1.0f/6.0f)};
  }
}

// ---------- launcher ----------
extern "C" void kernel_launch(void* const* d_in, const int* in_sizes, int n_in,
                              void* d_out, int out_size, void* d_ws, size_t ws_size,
                              hipStream_t stream){
  const float* X_de = (const float*)d_in[0];
  const float* W1   = (const float*)d_in[1];
  const float* b1   = (const float*)d_in[2];
  const float* ln1g = (const float*)d_in[3];
  const float* ln1b = (const float*)d_in[4];
  // d_in[5..8] (aw, ab, aln_g, aln_b) mathematically dead: LN over size-1 axis == aln_b
  const float* chw  = (const float*)d_in[9];
  const float* chb  = (const float*)d_in[10];
  const float* clng = (const float*)d_in[11];
  const float* clnb = (const float*)d_in[12];
  const float* sW1  = (const float*)d_in[13];
  const float* sb1  = (const float*)d_in[14];
  const float* slng = (const float*)d_in[15];
  const float* slnb = (const float*)d_in[16];
  const float* sW2  = (const float*)d_in[17];
  const float* sb2  = (const float*)d_in[18];

  float* out   = (float*)d_out;
  float* epoch = out;                        // (64,128,128)
  float* adj   = out + 1048576;              // (64,128,6,6)
  float* Xn    = out + 1343488;              // (64,128,6,128)
  float* G     = out + 7634944;              // (64,128,6,128)

  char* wsb  = (char*)d_ws;
  u16*   WT5   = (u16*)wsb;                   // 160KB (5 slots bf16 W^T)
  u16*   Sbuf  = (u16*)(wsb + 0x40000);       // 2MB  (S  bf16 [8192][128])
  u16*   Sgbuf = (u16*)(wsb + 0x240000);      // 2MB  (Sg bf16)
  float* T2    = (float*)(wsb + 0x440000);    // 4MB
  float* T4    = (float*)(wsb + 0x840000);    // 4MB

  hipLaunchKernelGGL(k_prep,  dim3(64),   dim3(256), 0, stream, W1, chw, sW1, WT5);
  hipLaunchKernelGGL(k_adj,   dim3(1152), dim3(256), 0, stream, adj);
  hipLaunchKernelGGL(k_fe,    dim3(1024), dim3(256), 0, stream, X_de, WT5, b1, ln1g, ln1b, Xn, Sbuf);
  hipLaunchKernelGGL(k_small, dim3(128),  dim3(256), 0, stream, Sbuf,  WT5 + 32768, chb, T2);
  hipLaunchKernelGGL(k_cheb,  dim3(1024), dim3(256), 0, stream, Xn, WT5, T2, clng, clnb, G, Sgbuf);
  hipLaunchKernelGGL(k_small, dim3(128),  dim3(256), 0, stream, Sgbuf, WT5 + 65536, sb1, T4);
  hipLaunchKernelGGL(k_satt,  dim3(1024), dim3(256), 0, stream, G, WT5, T4, slng, slnb, sW2, sb2, epoch);
}